// Round 10
// baseline (1378.195 us; speedup 1.0000x reference)
//
#include <hip/hip_runtime.h>
#include <cstdint>
#include <cstddef>

#define TT 2048   // tokens
#define HH 2048   // hidden
#define II 7168   // intermediate
#define EE 8      // experts
#define RR 159    // low rank
#define RPAD 192  // padded low-rank K (3 x 64)
#define ROWS 4096 // total compact rows = 2*TT

typedef __attribute__((ext_vector_type(8))) short bf16x8;
typedef __attribute__((ext_vector_type(4))) float f32x4;

__device__ __forceinline__ unsigned short f2bf(float f) {
  unsigned int u = __float_as_uint(f);
  u += 0x7fffu + ((u >> 16) & 1u);   // RNE
  return (unsigned short)(u >> 16);
}
__device__ __forceinline__ float bf2f(unsigned short u) {
  return __uint_as_float(((unsigned int)u) << 16);
}
// packed fp32x2 -> bf16x2
__device__ __forceinline__ unsigned int cvtpk(float lo, float hi) {
  unsigned int r;
  asm volatile("v_cvt_pk_bf16_f32 %0, %1, %2" : "=v"(r) : "v"(lo), "v"(hi));
  return r;
}
__device__ __forceinline__ bf16x8 zero8() {
  bf16x8 v;
#pragma unroll
  for (int j = 0; j < 8; j++) v[j] = 0;
  return v;
}
// async global->LDS, 16B per lane. LDS dest = wave-uniform base + lane*16.
__device__ __forceinline__ void gload16(const unsigned short* g, unsigned short* l) {
  __builtin_amdgcn_global_load_lds(
      (const __attribute__((address_space(1))) unsigned int*)g,
      (__attribute__((address_space(3))) unsigned int*)l, 16, 0, 0);
}

// ---------------- fp32 -> bf16 flat convert (V matrices only) ----------------
__global__ __launch_bounds__(256) void k_f2bf_flat(const float* __restrict__ s,
                                                   unsigned short* __restrict__ d,
                                                   long long n8) {
  long long i = (long long)blockIdx.x * blockDim.x + threadIdx.x;
  long long stride = (long long)gridDim.x * blockDim.x;
  for (; i < n8; i += stride) {
    const float* p = s + i * 8;
    float4 a = *(const float4*)p;
    float4 b = *(const float4*)(p + 4);
    bf16x8 v;
    v[0] = (short)f2bf(a.x); v[1] = (short)f2bf(a.y);
    v[2] = (short)f2bf(a.z); v[3] = (short)f2bf(a.w);
    v[4] = (short)f2bf(b.x); v[5] = (short)f2bf(b.y);
    v[6] = (short)f2bf(b.z); v[7] = (short)f2bf(b.w);
    *(bf16x8*)(d + i * 8) = v;
  }
}

// ---------------- U[rows][159] fp32 -> Up[rows][192] bf16 (zero pad) ----------------
__global__ __launch_bounds__(256) void k_upad(const float* __restrict__ U,
                                              unsigned short* __restrict__ Up, int rows) {
  long long idx = (long long)blockIdx.x * 256 + threadIdx.x;
  long long total = (long long)rows * 24;
  if (idx >= total) return;
  int row = (int)(idx / 24), c8 = (int)(idx % 24);
  unsigned short* dp = Up + (size_t)row * RPAD + c8 * 8;
#pragma unroll
  for (int j = 0; j < 8; j++) {
    int c = c8 * 8 + j;
    dp[j] = (c < RR) ? f2bf(U[(size_t)row * RR + c]) : (unsigned short)0;
  }
}

// ---------------- router ----------------
__global__ __launch_bounds__(256) void k_router(
    const float* __restrict__ x, const float* __restrict__ gw,
    float* __restrict__ logits_out, int* __restrict__ sel,
    float* __restrict__ wtok, int* __restrict__ counts) {
  int t = blockIdx.x;
  const float* xr = x + (size_t)t * HH;
  int base = threadIdx.x * 8;
  float4 x0 = *(const float4*)(xr + base);
  float4 x1 = *(const float4*)(xr + base + 4);
  float part[EE];
#pragma unroll
  for (int e = 0; e < EE; e++) {
    const float* g = gw + (size_t)e * HH + base;
    float4 g0 = *(const float4*)g;
    float4 g1 = *(const float4*)(g + 4);
    part[e] = x0.x * g0.x + x0.y * g0.y + x0.z * g0.z + x0.w * g0.w +
              x1.x * g1.x + x1.y * g1.y + x1.z * g1.z + x1.w * g1.w;
  }
#pragma unroll
  for (int off = 32; off > 0; off >>= 1)
#pragma unroll
    for (int e = 0; e < EE; e++) part[e] += __shfl_down(part[e], off);
  __shared__ float red[4][EE];
  int w = threadIdx.x >> 6, lane = threadIdx.x & 63;
  if (lane == 0) {
#pragma unroll
    for (int e = 0; e < EE; e++) red[w][e] = part[e];
  }
  __syncthreads();
  if (threadIdx.x == 0) {
    float lg[EE];
    float mx = -1e30f;
#pragma unroll
    for (int e = 0; e < EE; e++) {
      lg[e] = red[0][e] + red[1][e] + red[2][e] + red[3][e];
      logits_out[(size_t)t * EE + e] = lg[e];
      mx = fmaxf(mx, lg[e]);
    }
    float p[EE];
#pragma unroll
    for (int e = 0; e < EE; e++) p[e] = __expf(lg[e] - mx);
    int i0 = 0;
#pragma unroll
    for (int e = 1; e < EE; e++)
      if (lg[e] > lg[i0]) i0 = e;
    int i1 = (i0 == 0) ? 1 : 0;
#pragma unroll
    for (int e = 0; e < EE; e++)
      if (e != i0 && lg[e] > lg[i1]) i1 = e;
    float s = p[i0] + p[i1];
    sel[t * 2] = i0;
    sel[t * 2 + 1] = i1;
    wtok[t * 2] = p[i0] / s;
    wtok[t * 2 + 1] = p[i1] / s;
    atomicAdd(&counts[i0], 1);
    atomicAdd(&counts[i1], 1);
  }
}

// ---------------- prefix offsets ----------------
__global__ void k_offsets(const int* __restrict__ counts, int* __restrict__ offs,
                          int* __restrict__ curs) {
  if (threadIdx.x == 0 && blockIdx.x == 0) {
    int o = 0;
    for (int e = 0; e < EE; e++) {
      offs[e] = o;
      curs[e] = o;
      o += counts[e];
    }
    offs[EE] = o;
  }
}

// ---------------- build compact expert lists ----------------
__global__ void k_build(const int* __restrict__ sel, const float* __restrict__ wtok,
                        int* __restrict__ curs, int* __restrict__ rowsA,
                        float* __restrict__ rowwgt, int* __restrict__ rowid) {
  int t = blockIdx.x * blockDim.x + threadIdx.x;
  if (t >= TT) return;
  for (int k = 0; k < 2; k++) {
    int e = sel[t * 2 + k];
    int pos = atomicAdd(&curs[e], 1);
    rowsA[pos] = t;
    rowwgt[pos] = wtok[t * 2 + k];
    rowid[t * 2 + k] = pos;
  }
}

// ---------------- x -> bf16 ----------------
__global__ void k_x2bf(const float* __restrict__ x, unsigned short* __restrict__ xb) {
  size_t i = (size_t)blockIdx.x * blockDim.x + threadIdx.x;
  size_t n8 = (size_t)TT * HH / 8;
  size_t stride = (size_t)gridDim.x * blockDim.x;
  for (size_t idx = i; idx < n8; idx += stride) {
    const float* s = x + idx * 8;
    float4 a = *(const float4*)s;
    float4 b = *(const float4*)(s + 4);
    bf16x8 v;
    v[0] = (short)f2bf(a.x); v[1] = (short)f2bf(a.y);
    v[2] = (short)f2bf(a.z); v[3] = (short)f2bf(a.w);
    v[4] = (short)f2bf(b.x); v[5] = (short)f2bf(b.y);
    v[6] = (short)f2bf(b.z); v[7] = (short)f2bf(b.w);
    *(bf16x8*)(xb + idx * 8) = v;
  }
}

// ---------------- split-K low-rank GEMM: Pp = A @ V^T (fp32 partials) ----------------
template <bool GATHER>
__global__ __launch_bounds__(256, 2) void k_lowrank_sk(
    const unsigned short* __restrict__ Ab, int lda, int K, int kc, int NS,
    const unsigned short* __restrict__ V0, const unsigned short* __restrict__ V1,
    float* __restrict__ Pp,
    const int* __restrict__ counts, const int* __restrict__ offs,
    const int* __restrict__ rowsA) {
  int e = blockIdx.y;
  int cnt = counts[e];
  int m0 = blockIdx.x * 64;
  if (m0 >= cnt) return;
  int roff = offs[e];
  int mat = blockIdx.z / NS, split = blockIdx.z % NS;
  const unsigned short* V = ((mat == 0) ? V0 : V1) + (size_t)e * RR * K;
  float* Pout = Pp + (size_t)blockIdx.z * ROWS * RPAD;
  int kt0 = split * kc;
  int kt1 = kt0 + kc;
  if (kt1 > K) kt1 = K;
  __shared__ unsigned short As[64 * 64];
  __shared__ unsigned short Bs[192 * 64];
  int tid = threadIdx.x, lane = tid & 63, w = tid >> 6;
  int rstage = tid >> 3, cg = tid & 7;
  f32x4 acc[12];
#pragma unroll
  for (int n = 0; n < 12; n++) acc[n] = (f32x4){0.f, 0.f, 0.f, 0.f};
  for (int kt = kt0; kt < kt1; kt += 64) {
#pragma unroll
    for (int p = 0; p < 2; p++) {
      int r = p * 32 + rstage;
      bf16x8 v = zero8();
      int gr = m0 + r;
      if (gr < cnt) {
        size_t arow = GATHER ? (size_t)rowsA[roff + gr] : (size_t)(roff + gr);
        v = *(const bf16x8*)(Ab + arow * (size_t)lda + kt + cg * 8);
      }
      *(bf16x8*)&As[r * 64 + ((cg ^ (r & 7)) * 8)] = v;
    }
#pragma unroll
    for (int p = 0; p < 6; p++) {
      int r = p * 32 + rstage;
      bf16x8 v = zero8();
      if (r < RR) v = *(const bf16x8*)(V + (size_t)r * K + kt + cg * 8);
      *(bf16x8*)&Bs[r * 64 + ((cg ^ (r & 7)) * 8)] = v;
    }
    __syncthreads();
#pragma unroll
    for (int ks = 0; ks < 2; ks++) {
      int rA = w * 16 + (lane & 15);
      bf16x8 a = *(const bf16x8*)&As[rA * 64 + (((ks * 4 + (lane >> 4)) ^ (rA & 7)) * 8)];
#pragma unroll
      for (int n = 0; n < 12; n++) {
        int rB = n * 16 + (lane & 15);
        bf16x8 b = *(const bf16x8*)&Bs[rB * 64 + (((ks * 4 + (lane >> 4)) ^ (rB & 7)) * 8)];
        acc[n] = __builtin_amdgcn_mfma_f32_16x16x32_bf16(a, b, acc[n], 0, 0, 0);
      }
    }
    __syncthreads();
  }
  int mbase = m0 + w * 16 + (lane >> 4) * 4;
#pragma unroll
  for (int n = 0; n < 12; n++) {
    int col = n * 16 + (lane & 15);
#pragma unroll
    for (int r4 = 0; r4 < 4; r4++) {
      int row = mbase + r4;
      if (row < cnt) Pout[(size_t)(roff + row) * RPAD + col] = acc[n][r4];
    }
  }
}

// ---------------- reduce split-K partials -> bf16 P ----------------
__global__ __launch_bounds__(256) void k_lr_reduce(
    const float* __restrict__ Pp, unsigned short* __restrict__ P0,
    unsigned short* __restrict__ P1m, int NS, int nmat) {
  long long idx = (long long)blockIdx.x * 256 + threadIdx.x;
  long long total = (long long)nmat * ROWS * 24;
  if (idx >= total) return;
  int mat = (int)(idx / ((long long)ROWS * 24));
  int rem = (int)(idx % ((long long)ROWS * 24));
  int row = rem / 24, c8 = rem % 24;
  const float* base = Pp + ((size_t)mat * NS) * ROWS * RPAD + (size_t)row * RPAD + c8 * 8;
  float s0 = 0, s1 = 0, s2 = 0, s3 = 0, s4 = 0, s5 = 0, s6 = 0, s7 = 0;
  for (int sp = 0; sp < NS; sp++) {
    const float* p = base + (size_t)sp * ROWS * RPAD;
    float4 a = *(const float4*)p;
    float4 b = *(const float4*)(p + 4);
    s0 += a.x; s1 += a.y; s2 += a.z; s3 += a.w;
    s4 += b.x; s5 += b.y; s6 += b.z; s7 += b.w;
  }
  bf16x8 v;
  v[0] = (short)f2bf(s0); v[1] = (short)f2bf(s1);
  v[2] = (short)f2bf(s2); v[3] = (short)f2bf(s3);
  v[4] = (short)f2bf(s4); v[5] = (short)f2bf(s5);
  v[6] = (short)f2bf(s6); v[7] = (short)f2bf(s7);
  unsigned short* P = (mat == 0) ? P0 : P1m;
  *(bf16x8*)(P + (size_t)row * RPAD + c8 * 8) = v;
}

// ============ 2-PHASE PIPELINED GEMM: BM=128, BN=128, BK=64, LDS dbuf ============
// Per K-step: {issue A-DMA(t+1)->As[nxt], load W-regs(t+1)} -> MFMA on buf[cur]
// -> cvt+ds_write W(t+1)->Bs[nxt] -> ONE barrier. The A-DMA has the whole
// ds_read+MFMA phase to complete before the barrier's implicit vmcnt(0) drain.
// MODE 0 (GATE): out = A(Xb,gather)@W1^T + P1@U1^T              -> bf16 Gbuf
// MODE 1 (UP):   u = A(Xb,gather)@W3^T + P3@U3^T; h=silu(g)*u   -> bf16 hmid
// MODE 2 (DOWN): y = (A(hmid)@W2^T + P2@U2^T)*rowwgt            -> fp32 ybuf
template <int MODE>
__global__ __launch_bounds__(256, 2) void k_gemm2(
    const unsigned short* __restrict__ Ab, int K, int N,
    const float* __restrict__ Wf,
    const unsigned short* __restrict__ Pq,
    const unsigned short* __restrict__ Uq,
    const unsigned short* __restrict__ Gb,
    const float* __restrict__ rowwgt,
    unsigned short* __restrict__ outb,
    float* __restrict__ outf,
    const int* __restrict__ counts, const int* __restrict__ offs,
    const int* __restrict__ rowsA) {
  int e = blockIdx.z;
  int cnt = counts[e];
  int m0 = blockIdx.y * 128;
  if (m0 >= cnt) return;
  int n0 = blockIdx.x * 128;
  int roff = offs[e];
  const float* w = Wf + (size_t)e * (size_t)N * K;
  const unsigned short* uq = Uq + (size_t)e * (size_t)N * RPAD;
  __shared__ unsigned short As[2][128 * 64];  // 2 x 16 KB
  __shared__ unsigned short Bs[2][128 * 64];  // 2 x 16 KB
  int tid = threadIdx.x, lane = tid & 63, wv = tid >> 6;
  int wr = (wv >> 1) * 64, wc = (wv & 1) * 64;
  f32x4 acc[4][4];
#pragma unroll
  for (int m = 0; m < 4; m++)
#pragma unroll
    for (int n = 0; n < 4; n++) acc[m][n] = (f32x4){0.f, 0.f, 0.f, 0.f};
  // staging geometry: wave wv covers rows [wv*32,wv*32+32); instr i covers 8 rows;
  // lane -> (row += lane>>3, col-slot lane&7). Global col pre-swizzled (same
  // involution as the ds_read XOR) so linear LDS dest == swizzled layout.
  int srow = (wv << 5) + (lane >> 3);
  int swz = (((lane & 7) ^ ((lane >> 3) & 7)) << 3);
  int aoff[4], woff[4];
#pragma unroll
  for (int i = 0; i < 4; i++) {
    int gr = m0 + srow + i * 8;
    if (gr >= cnt) gr = cnt - 1;  // clamp: garbage rows masked at store
    int arow = (MODE < 2) ? rowsA[roff + gr] : (roff + gr);
    aoff[i] = arow * K + swz;
    woff[i] = (n0 + srow + i * 8) * K + swz;
  }
  // prologue: stage tile 0 into buffer 0 (A via DMA, W via regs+cvt)
  float4 rb[4][2];
#pragma unroll
  for (int i = 0; i < 4; i++) {
    gload16(Ab + aoff[i], &As[0][((wv << 5) + (i << 3)) * 64]);
    rb[i][0] = *(const float4*)(w + woff[i]);
    rb[i][1] = *(const float4*)(w + woff[i] + 4);
  }
#pragma unroll
  for (int i = 0; i < 4; i++) {
    int idx = (srow + i * 8) * 64 + (lane & 7) * 8;
    uint4 q;
    q.x = cvtpk(rb[i][0].x, rb[i][0].y);
    q.y = cvtpk(rb[i][0].z, rb[i][0].w);
    q.z = cvtpk(rb[i][1].x, rb[i][1].y);
    q.w = cvtpk(rb[i][1].z, rb[i][1].w);
    *(uint4*)&Bs[0][idx] = q;
  }
  __syncthreads();
  int nt = K >> 6;
  for (int t = 0; t < nt; ++t) {
    int cur = t & 1, nxt = cur ^ 1;
    bool more = (t + 1 < nt);
    if (more) {
      // issue next-tile loads FIRST: DMA latency hides under this tile's MFMA
#pragma unroll
      for (int i = 0; i < 4; i++) {
        gload16(Ab + aoff[i] + (t + 1) * 64, &As[nxt][((wv << 5) + (i << 3)) * 64]);
        rb[i][0] = *(const float4*)(w + woff[i] + (t + 1) * 64);
        rb[i][1] = *(const float4*)(w + woff[i] + (t + 1) * 64 + 4);
      }
    }
#pragma unroll
    for (int ks = 0; ks < 2; ks++) {
      bf16x8 af[4], bsr[4];
#pragma unroll
      for (int m = 0; m < 4; m++) {
        int r = wr + m * 16 + (lane & 15);
        af[m] = *(const bf16x8*)&As[cur][r * 64 + (((ks * 4 + (lane >> 4)) ^ (r & 7)) * 8)];
      }
#pragma unroll
      for (int n = 0; n < 4; n++) {
        int r = wc + n * 16 + (lane & 15);
        bsr[n] = *(const bf16x8*)&Bs[cur][r * 64 + (((ks * 4 + (lane >> 4)) ^ (r & 7)) * 8)];
      }
#pragma unroll
      for (int m = 0; m < 4; m++)
#pragma unroll
        for (int n = 0; n < 4; n++)
          acc[m][n] = __builtin_amdgcn_mfma_f32_16x16x32_bf16(af[m], bsr[n], acc[m][n], 0, 0, 0);
    }
    if (more) {
      // write next W tile into the other buffer (no race with cur readers)
#pragma unroll
      for (int i = 0; i < 4; i++) {
        int idx = (srow + i * 8) * 64 + (lane & 7) * 8;
        uint4 q;
        q.x = cvtpk(rb[i][0].x, rb[i][0].y);
        q.y = cvtpk(rb[i][0].z, rb[i][0].w);
        q.z = cvtpk(rb[i][1].x, rb[i][1].y);
        q.w = cvtpk(rb[i][1].z, rb[i][1].w);
        *(uint4*)&Bs[nxt][idx] = q;
      }
    }
    __syncthreads();  // drains A-DMA(t+1) (issued ~whole MFMA phase ago) + ds_writes
  }
  // low-rank K-extension: acc += P@U^T (bf16, DMA both; classic 2-barrier, 3 steps)
  for (int kt = 0; kt < RPAD; kt += 64) {
#pragma unroll
    for (int i = 0; i < 4; i++) {
      int gr = m0 + srow + i * 8;
      if (gr >= cnt) gr = cnt - 1;
      gload16(Pq + (size_t)(roff + gr) * RPAD + swz + kt, &As[0][((wv << 5) + (i << 3)) * 64]);
      gload16(uq + (size_t)(n0 + srow + i * 8) * RPAD + swz + kt,
              &Bs[0][((wv << 5) + (i << 3)) * 64]);
    }
    __syncthreads();
#pragma unroll
    for (int ks = 0; ks < 2; ks++) {
      bf16x8 af[4], bsr[4];
#pragma unroll
      for (int m = 0; m < 4; m++) {
        int r = wr + m * 16 + (lane & 15);
        af[m] = *(const bf16x8*)&As[0][r * 64 + (((ks * 4 + (lane >> 4)) ^ (r & 7)) * 8)];
      }
#pragma unroll
      for (int n = 0; n < 4; n++) {
        int r = wc + n * 16 + (lane & 15);
        bsr[n] = *(const bf16x8*)&Bs[0][r * 64 + (((ks * 4 + (lane >> 4)) ^ (r & 7)) * 8)];
      }
#pragma unroll
      for (int m = 0; m < 4; m++)
#pragma unroll
        for (int n = 0; n < 4; n++)
          acc[m][n] = __builtin_amdgcn_mfma_f32_16x16x32_bf16(af[m], bsr[n], acc[m][n], 0, 0, 0);
    }
    __syncthreads();
  }
  // epilogue per MODE
#pragma unroll
  for (int m = 0; m < 4; m++) {
#pragma unroll
    for (int r4 = 0; r4 < 4; r4++) {
      int row = m0 + wr + m * 16 + (lane >> 4) * 4 + r4;
      if (row < cnt) {
        size_t rbase = (size_t)(roff + row) * N + n0 + wc;
        if constexpr (MODE == 0) {
#pragma unroll
          for (int n = 0; n < 4; n++)
            outb[rbase + n * 16 + (lane & 15)] = f2bf(acc[m][n][r4]);
        } else if constexpr (MODE == 1) {
#pragma unroll
          for (int n = 0; n < 4; n++) {
            float g = bf2f(Gb[rbase + n * 16 + (lane & 15)]);
            float uu = acc[m][n][r4];
            float h = (g / (1.f + __expf(-g))) * uu;
            outb[rbase + n * 16 + (lane & 15)] = f2bf(h);
          }
        } else {
          float wgt = rowwgt[roff + row];
#pragma unroll
          for (int n = 0; n < 4; n++)
            outf[rbase + n * 16 + (lane & 15)] = acc[m][n][r4] * wgt;
        }
      }
    }
  }
}

// ---------------- combine: out[t] = y[row0] + y[row1] ----------------
__global__ void k_combine(const float* __restrict__ ybuf, const int* __restrict__ rowid,
                          float* __restrict__ out) {
  int idx = blockIdx.x * 256 + threadIdx.x;
  int t = idx >> 8;
  int c = (idx & 255) * 8;
  int r0 = rowid[t * 2], r1 = rowid[t * 2 + 1];
  const float* y0 = ybuf + (size_t)r0 * HH + c;
  const float* y1 = ybuf + (size_t)r1 * HH + c;
  float4 a0 = *(const float4*)y0, a1 = *(const float4*)(y0 + 4);
  float4 b0 = *(const float4*)y1, b1 = *(const float4*)(y1 + 4);
  float4 o0 = {a0.x + b0.x, a0.y + b0.y, a0.z + b0.z, a0.w + b0.w};
  float4 o1 = {a1.x + b1.x, a1.y + b1.y, a1.z + b1.z, a1.w + b1.w};
  float* o = out + (size_t)t * HH + c;
  *(float4*)o = o0;
  *(float4*)(o + 4) = o1;
}

extern "C" void kernel_launch(void* const* d_in, const int* in_sizes, int n_in,
                              void* d_out, int out_size, void* d_ws, size_t ws_size,
                              hipStream_t stream) {
  const float* x  = (const float*)d_in[0];
  const float* gw = (const float*)d_in[1];
  const float* W1 = (const float*)d_in[2];
  const float* W2 = (const float*)d_in[3];
  const float* W3 = (const float*)d_in[4];
  const float* U1 = (const float*)d_in[5];
  const float* V1 = (const float*)d_in[6];
  const float* U2 = (const float*)d_in[7];
  const float* V2 = (const float*)d_in[8];
  const float* U3 = (const float*)d_in[9];
  const float* V3 = (const float*)d_in[10];
  float* out = (float*)d_out;
  float* logits = out + (size_t)TT * HH;

  char* ws = (char*)d_ws;
  size_t off = 0;
  auto take = [&](size_t b) -> char* {
    char* p = ws + off;
    off += (b + 255) & ~(size_t)255;
    return p;
  };
  unsigned short* Xb   = (unsigned short*)take((size_t)TT * HH * 2);
  unsigned short* hmid = (unsigned short*)take((size_t)ROWS * II * 2);
  unsigned short* Gbuf = (unsigned short*)take((size_t)ROWS * II * 2);
  unsigned short* P1   = (unsigned short*)take((size_t)ROWS * RPAD * 2);
  unsigned short* P3   = (unsigned short*)take((size_t)ROWS * RPAD * 2);
  unsigned short* P2   = (unsigned short*)take((size_t)ROWS * RPAD * 2);
  float* ybuf          = (float*)take((size_t)ROWS * HH * 4);
  int* sel             = (int*)take((size_t)TT * 2 * 4);
  float* wtok          = (float*)take((size_t)TT * 2 * 4);
  int* rowsA           = (int*)take((size_t)ROWS * 4);
  float* rowwgt        = (float*)take((size_t)ROWS * 4);
  int* rowid           = (int*)take((size_t)TT * 2 * 4);
  int* meta            = (int*)take(1024);
  int* counts  = meta;
  int* offs    = meta + 16;
  int* curs    = meta + 32;
  unsigned short* V1b = (unsigned short*)take((size_t)EE * RR * HH * 2);
  unsigned short* V3b = (unsigned short*)take((size_t)EE * RR * HH * 2);
  unsigned short* V2b = (unsigned short*)take((size_t)EE * RR * II * 2);
  unsigned short* U1p = (unsigned short*)take((size_t)EE * II * RPAD * 2);
  unsigned short* U3p = (unsigned short*)take((size_t)EE * II * RPAD * 2);
  unsigned short* U2p = (unsigned short*)take((size_t)EE * HH * RPAD * 2);
  float* Pp           = (float*)take((size_t)8 * ROWS * RPAD * 4);

  hipMemsetAsync(counts, 0, EE * sizeof(int), stream);
  k_f2bf_flat<<<1024, 256, 0, stream>>>(V1, V1b, (long long)EE * RR * HH / 8);
  k_f2bf_flat<<<1024, 256, 0, stream>>>(V3, V3b, (long long)EE * RR * HH / 8);
  k_f2bf_flat<<<1024, 256, 0, stream>>>(V2, V2b, (long long)EE * RR * II / 8);
  k_upad<<<(EE * II * 24 + 255) / 256, 256, 0, stream>>>(U1, U1p, EE * II);
  k_upad<<<(EE * II * 24 + 255) / 256, 256, 0, stream>>>(U3, U3p, EE * II);
  k_upad<<<(EE * HH * 24 + 255) / 256, 256, 0, stream>>>(U2, U2p, EE * HH);
  k_router<<<TT, 256, 0, stream>>>(x, gw, logits, sel, wtok, counts);
  k_offsets<<<1, 64, 0, stream>>>(counts, offs, curs);
  k_build<<<TT / 256, 256, 0, stream>>>(sel, wtok, curs, rowsA, rowwgt, rowid);
  k_x2bf<<<2048, 256, 0, stream>>>(x, Xb);
  // P1/P3 = Xb(gathered) @ {V1,V3}^T : K=2048, split x4
  k_lowrank_sk<true><<<dim3(TT / 64, EE, 2 * 4), 256, 0, stream>>>(
      Xb, HH, HH, 512, 4, V1b, V3b, Pp, counts, offs, rowsA);
  k_lr_reduce<<<(2 * ROWS * 24 + 255) / 256, 256, 0, stream>>>(Pp, P1, P3, 4, 2);
  // gate then up (fused silu-mul in up's epilogue); n innermost (L3 W reuse)
  k_gemm2<0><<<dim3(II / 128, TT / 128, EE), 256, 0, stream>>>(
      Xb, HH, II, W1, P1, U1p, nullptr, nullptr, Gbuf, nullptr, counts, offs, rowsA);
  k_gemm2<1><<<dim3(II / 128, TT / 128, EE), 256, 0, stream>>>(
      Xb, HH, II, W3, P3, U3p, Gbuf, nullptr, hmid, nullptr, counts, offs, rowsA);
  // P2 = hmid @ V2^T : K=7168, split x8
  k_lowrank_sk<false><<<dim3(TT / 64, EE, 8), 256, 0, stream>>>(
      hmid, II, II, 896, 8, V2b, V2b, Pp, counts, offs, rowsA);
  k_lr_reduce<<<(ROWS * 24 + 255) / 256, 256, 0, stream>>>(Pp, P2, P2, 8, 1);
  k_gemm2<2><<<dim3(HH / 128, TT / 128, EE), 256, 0, stream>>>(
      hmid, II, HH, W2, P2, U2p, nullptr, rowwgt, nullptr, ybuf, counts, offs, rowsA);
  k_combine<<<(TT * HH / 8) / 256, 256, 0, stream>>>(ybuf, rowid, out);
}

// Round 11
// 1170.386 us; speedup vs baseline: 1.1776x; 1.1776x over previous
//
#include <hip/hip_runtime.h>
#include <cstdint>
#include <cstddef>

#define TT 2048   // tokens
#define HH 2048   // hidden
#define II 7168   // intermediate
#define EE 8      // experts
#define RR 159    // low rank
#define RPAD 192  // padded low-rank K (3 x 64)
#define ROWS 4096 // total compact rows = 2*TT

typedef __attribute__((ext_vector_type(8))) short bf16x8;
typedef __attribute__((ext_vector_type(4))) float f32x4;

__device__ __forceinline__ unsigned short f2bf(float f) {
  unsigned int u = __float_as_uint(f);
  u += 0x7fffu + ((u >> 16) & 1u);   // RNE
  return (unsigned short)(u >> 16);
}
__device__ __forceinline__ float bf2f(unsigned short u) {
  return __uint_as_float(((unsigned int)u) << 16);
}
// packed fp32x2 -> bf16x2
__device__ __forceinline__ unsigned int cvtpk(float lo, float hi) {
  unsigned int r;
  asm volatile("v_cvt_pk_bf16_f32 %0, %1, %2" : "=v"(r) : "v"(lo), "v"(hi));
  return r;
}
__device__ __forceinline__ bf16x8 zero8() {
  bf16x8 v;
#pragma unroll
  for (int j = 0; j < 8; j++) v[j] = 0;
  return v;
}
// async global->LDS, 16B per lane. LDS dest = wave-uniform base + lane*16.
__device__ __forceinline__ void gload16(const unsigned short* g, unsigned short* l) {
  __builtin_amdgcn_global_load_lds(
      (const __attribute__((address_space(1))) unsigned int*)g,
      (__attribute__((address_space(3))) unsigned int*)l, 16, 0, 0);
}

// ---------------- fp32 -> bf16 flat convert (V matrices only) ----------------
__global__ __launch_bounds__(256) void k_f2bf_flat(const float* __restrict__ s,
                                                   unsigned short* __restrict__ d,
                                                   long long n8) {
  long long i = (long long)blockIdx.x * blockDim.x + threadIdx.x;
  long long stride = (long long)gridDim.x * blockDim.x;
  for (; i < n8; i += stride) {
    const float* p = s + i * 8;
    float4 a = *(const float4*)p;
    float4 b = *(const float4*)(p + 4);
    bf16x8 v;
    v[0] = (short)f2bf(a.x); v[1] = (short)f2bf(a.y);
    v[2] = (short)f2bf(a.z); v[3] = (short)f2bf(a.w);
    v[4] = (short)f2bf(b.x); v[5] = (short)f2bf(b.y);
    v[6] = (short)f2bf(b.z); v[7] = (short)f2bf(b.w);
    *(bf16x8*)(d + i * 8) = v;
  }
}

// ---------------- U[rows][159] fp32 -> Up[rows][192] bf16 (zero pad) ----------------
__global__ __launch_bounds__(256) void k_upad(const float* __restrict__ U,
                                              unsigned short* __restrict__ Up, int rows) {
  long long idx = (long long)blockIdx.x * 256 + threadIdx.x;
  long long total = (long long)rows * 24;
  if (idx >= total) return;
  int row = (int)(idx / 24), c8 = (int)(idx % 24);
  unsigned short* dp = Up + (size_t)row * RPAD + c8 * 8;
#pragma unroll
  for (int j = 0; j < 8; j++) {
    int c = c8 * 8 + j;
    dp[j] = (c < RR) ? f2bf(U[(size_t)row * RR + c]) : (unsigned short)0;
  }
}

// ---------------- router ----------------
__global__ __launch_bounds__(256) void k_router(
    const float* __restrict__ x, const float* __restrict__ gw,
    float* __restrict__ logits_out, int* __restrict__ sel,
    float* __restrict__ wtok, int* __restrict__ counts) {
  int t = blockIdx.x;
  const float* xr = x + (size_t)t * HH;
  int base = threadIdx.x * 8;
  float4 x0 = *(const float4*)(xr + base);
  float4 x1 = *(const float4*)(xr + base + 4);
  float part[EE];
#pragma unroll
  for (int e = 0; e < EE; e++) {
    const float* g = gw + (size_t)e * HH + base;
    float4 g0 = *(const float4*)g;
    float4 g1 = *(const float4*)(g + 4);
    part[e] = x0.x * g0.x + x0.y * g0.y + x0.z * g0.z + x0.w * g0.w +
              x1.x * g1.x + x1.y * g1.y + x1.z * g1.z + x1.w * g1.w;
  }
#pragma unroll
  for (int off = 32; off > 0; off >>= 1)
#pragma unroll
    for (int e = 0; e < EE; e++) part[e] += __shfl_down(part[e], off);
  __shared__ float red[4][EE];
  int w = threadIdx.x >> 6, lane = threadIdx.x & 63;
  if (lane == 0) {
#pragma unroll
    for (int e = 0; e < EE; e++) red[w][e] = part[e];
  }
  __syncthreads();
  if (threadIdx.x == 0) {
    float lg[EE];
    float mx = -1e30f;
#pragma unroll
    for (int e = 0; e < EE; e++) {
      lg[e] = red[0][e] + red[1][e] + red[2][e] + red[3][e];
      logits_out[(size_t)t * EE + e] = lg[e];
      mx = fmaxf(mx, lg[e]);
    }
    float p[EE];
#pragma unroll
    for (int e = 0; e < EE; e++) p[e] = __expf(lg[e] - mx);
    int i0 = 0;
#pragma unroll
    for (int e = 1; e < EE; e++)
      if (lg[e] > lg[i0]) i0 = e;
    int i1 = (i0 == 0) ? 1 : 0;
#pragma unroll
    for (int e = 0; e < EE; e++)
      if (e != i0 && lg[e] > lg[i1]) i1 = e;
    float s = p[i0] + p[i1];
    sel[t * 2] = i0;
    sel[t * 2 + 1] = i1;
    wtok[t * 2] = p[i0] / s;
    wtok[t * 2 + 1] = p[i1] / s;
    atomicAdd(&counts[i0], 1);
    atomicAdd(&counts[i1], 1);
  }
}

// ---------------- prefix offsets ----------------
__global__ void k_offsets(const int* __restrict__ counts, int* __restrict__ offs,
                          int* __restrict__ curs) {
  if (threadIdx.x == 0 && blockIdx.x == 0) {
    int o = 0;
    for (int e = 0; e < EE; e++) {
      offs[e] = o;
      curs[e] = o;
      o += counts[e];
    }
    offs[EE] = o;
  }
}

// ---------------- build compact expert lists ----------------
__global__ void k_build(const int* __restrict__ sel, const float* __restrict__ wtok,
                        int* __restrict__ curs, int* __restrict__ rowsA,
                        float* __restrict__ rowwgt, int* __restrict__ rowid) {
  int t = blockIdx.x * blockDim.x + threadIdx.x;
  if (t >= TT) return;
  for (int k = 0; k < 2; k++) {
    int e = sel[t * 2 + k];
    int pos = atomicAdd(&curs[e], 1);
    rowsA[pos] = t;
    rowwgt[pos] = wtok[t * 2 + k];
    rowid[t * 2 + k] = pos;
  }
}

// ---------------- x -> bf16 ----------------
__global__ void k_x2bf(const float* __restrict__ x, unsigned short* __restrict__ xb) {
  size_t i = (size_t)blockIdx.x * blockDim.x + threadIdx.x;
  size_t n8 = (size_t)TT * HH / 8;
  size_t stride = (size_t)gridDim.x * blockDim.x;
  for (size_t idx = i; idx < n8; idx += stride) {
    const float* s = x + idx * 8;
    float4 a = *(const float4*)s;
    float4 b = *(const float4*)(s + 4);
    bf16x8 v;
    v[0] = (short)f2bf(a.x); v[1] = (short)f2bf(a.y);
    v[2] = (short)f2bf(a.z); v[3] = (short)f2bf(a.w);
    v[4] = (short)f2bf(b.x); v[5] = (short)f2bf(b.y);
    v[6] = (short)f2bf(b.z); v[7] = (short)f2bf(b.w);
    *(bf16x8*)(xb + idx * 8) = v;
  }
}

// ---------------- split-K low-rank GEMM: Pp = A @ V^T (fp32 partials) ----------------
template <bool GATHER>
__global__ __launch_bounds__(256, 2) void k_lowrank_sk(
    const unsigned short* __restrict__ Ab, int lda, int K, int kc, int NS,
    const unsigned short* __restrict__ V0, const unsigned short* __restrict__ V1,
    float* __restrict__ Pp,
    const int* __restrict__ counts, const int* __restrict__ offs,
    const int* __restrict__ rowsA) {
  int e = blockIdx.y;
  int cnt = counts[e];
  int m0 = blockIdx.x * 64;
  if (m0 >= cnt) return;
  int roff = offs[e];
  int mat = blockIdx.z / NS, split = blockIdx.z % NS;
  const unsigned short* V = ((mat == 0) ? V0 : V1) + (size_t)e * RR * K;
  float* Pout = Pp + (size_t)blockIdx.z * ROWS * RPAD;
  int kt0 = split * kc;
  int kt1 = kt0 + kc;
  if (kt1 > K) kt1 = K;
  __shared__ unsigned short As[64 * 64];
  __shared__ unsigned short Bs[192 * 64];
  int tid = threadIdx.x, lane = tid & 63, w = tid >> 6;
  int rstage = tid >> 3, cg = tid & 7;
  f32x4 acc[12];
#pragma unroll
  for (int n = 0; n < 12; n++) acc[n] = (f32x4){0.f, 0.f, 0.f, 0.f};
  for (int kt = kt0; kt < kt1; kt += 64) {
#pragma unroll
    for (int p = 0; p < 2; p++) {
      int r = p * 32 + rstage;
      bf16x8 v = zero8();
      int gr = m0 + r;
      if (gr < cnt) {
        size_t arow = GATHER ? (size_t)rowsA[roff + gr] : (size_t)(roff + gr);
        v = *(const bf16x8*)(Ab + arow * (size_t)lda + kt + cg * 8);
      }
      *(bf16x8*)&As[r * 64 + ((cg ^ (r & 7)) * 8)] = v;
    }
#pragma unroll
    for (int p = 0; p < 6; p++) {
      int r = p * 32 + rstage;
      bf16x8 v = zero8();
      if (r < RR) v = *(const bf16x8*)(V + (size_t)r * K + kt + cg * 8);
      *(bf16x8*)&Bs[r * 64 + ((cg ^ (r & 7)) * 8)] = v;
    }
    __syncthreads();
#pragma unroll
    for (int ks = 0; ks < 2; ks++) {
      int rA = w * 16 + (lane & 15);
      bf16x8 a = *(const bf16x8*)&As[rA * 64 + (((ks * 4 + (lane >> 4)) ^ (rA & 7)) * 8)];
#pragma unroll
      for (int n = 0; n < 12; n++) {
        int rB = n * 16 + (lane & 15);
        bf16x8 b = *(const bf16x8*)&Bs[rB * 64 + (((ks * 4 + (lane >> 4)) ^ (rB & 7)) * 8)];
        acc[n] = __builtin_amdgcn_mfma_f32_16x16x32_bf16(a, b, acc[n], 0, 0, 0);
      }
    }
    __syncthreads();
  }
  int mbase = m0 + w * 16 + (lane >> 4) * 4;
#pragma unroll
  for (int n = 0; n < 12; n++) {
    int col = n * 16 + (lane & 15);
#pragma unroll
    for (int r4 = 0; r4 < 4; r4++) {
      int row = mbase + r4;
      if (row < cnt) Pout[(size_t)(roff + row) * RPAD + col] = acc[n][r4];
    }
  }
}

// ---------------- reduce split-K partials -> bf16 P ----------------
__global__ __launch_bounds__(256) void k_lr_reduce(
    const float* __restrict__ Pp, unsigned short* __restrict__ P0,
    unsigned short* __restrict__ P1m, int NS, int nmat) {
  long long idx = (long long)blockIdx.x * 256 + threadIdx.x;
  long long total = (long long)nmat * ROWS * 24;
  if (idx >= total) return;
  int mat = (int)(idx / ((long long)ROWS * 24));
  int rem = (int)(idx % ((long long)ROWS * 24));
  int row = rem / 24, c8 = rem % 24;
  const float* base = Pp + ((size_t)mat * NS) * ROWS * RPAD + (size_t)row * RPAD + c8 * 8;
  float s0 = 0, s1 = 0, s2 = 0, s3 = 0, s4 = 0, s5 = 0, s6 = 0, s7 = 0;
  for (int sp = 0; sp < NS; sp++) {
    const float* p = base + (size_t)sp * ROWS * RPAD;
    float4 a = *(const float4*)p;
    float4 b = *(const float4*)(p + 4);
    s0 += a.x; s1 += a.y; s2 += a.z; s3 += a.w;
    s4 += b.x; s5 += b.y; s6 += b.z; s7 += b.w;
  }
  bf16x8 v;
  v[0] = (short)f2bf(s0); v[1] = (short)f2bf(s1);
  v[2] = (short)f2bf(s2); v[3] = (short)f2bf(s3);
  v[4] = (short)f2bf(s4); v[5] = (short)f2bf(s5);
  v[6] = (short)f2bf(s6); v[7] = (short)f2bf(s7);
  unsigned short* P = (mat == 0) ? P0 : P1m;
  *(bf16x8*)(P + (size_t)row * RPAD + c8 * 8) = v;
}

// ============ BIG GEMM: BM=256, BN=128, BK=64, all three modes ============
// Wave wv owns output rows [wv*64, wv*64+64) x all 128 cols: acc[4][8].
// 64 MFMA per K-step per wave -> barrier amortization. 48 KB LDS, no dbuf
// (occupancy > explicit pipelining on this family — round-10 lesson).
// A (bf16) via 8x gload16/wave; W fp32 reg-staged w/ one-step prefetch.
// MODE 0 (GATE): out = A(Xb,gather)@W1^T + P1@U1^T              -> bf16 Gbuf
// MODE 1 (UP):   u = A(Xb,gather)@W3^T + P3@U3^T; h=silu(g)*u   -> bf16 hmid
// MODE 2 (DOWN): y = (A(hmid)@W2^T + P2@U2^T)*rowwgt            -> fp32 ybuf
// Grid: x=n (innermost, L3 W reuse), y=m, z=e.
template <int MODE>
__global__ __launch_bounds__(256, 2) void k_gemm_big(
    const unsigned short* __restrict__ Ab, int K, int N,
    const float* __restrict__ Wf,
    const unsigned short* __restrict__ Pq,
    const unsigned short* __restrict__ Uq,
    const unsigned short* __restrict__ Gb,
    const float* __restrict__ rowwgt,
    unsigned short* __restrict__ outb,
    float* __restrict__ outf,
    const int* __restrict__ counts, const int* __restrict__ offs,
    const int* __restrict__ rowsA) {
  int e = blockIdx.z;
  int cnt = counts[e];
  int m0 = blockIdx.y * 256;
  if (m0 >= cnt) return;
  int n0 = blockIdx.x * 128;
  int roff = offs[e];
  const float* w = Wf + (size_t)e * (size_t)N * K;
  const unsigned short* uq = Uq + (size_t)e * (size_t)N * RPAD;
  __shared__ unsigned short As[256 * 64];   // 32 KB
  __shared__ unsigned short Bs[128 * 64];   // 16 KB
  int tid = threadIdx.x, lane = tid & 63, wv = tid >> 6;
  f32x4 acc[4][8];
#pragma unroll
  for (int m = 0; m < 4; m++)
#pragma unroll
    for (int n = 0; n < 8; n++) acc[m][n] = (f32x4){0.f, 0.f, 0.f, 0.f};
  int swz = (((lane & 7) ^ ((lane >> 3) & 7)) << 3);
  // A rows: wave wv stages rows [wv*64, wv*64+64), 8 instrs x 8 rows
  int srowA = (wv << 6) + (lane >> 3);
  int aoff[8];   // element offsets into Ab (int; max ~30M ok)
#pragma unroll
  for (int i = 0; i < 8; i++) {
    int gr = m0 + srowA + i * 8;
    if (gr >= cnt) gr = cnt - 1;  // clamp: garbage rows masked at store
    int arow = (MODE < 2) ? rowsA[roff + gr] : (roff + gr);
    aoff[i] = arow * K + swz;
  }
  // B rows: 128 total, wave wv stages rows [wv*32, wv*32+32), 4 iters
  int srowB = (wv << 5) + (lane >> 3);
  int woff[4];
#pragma unroll
  for (int i = 0; i < 4; i++) woff[i] = (n0 + srowB + i * 8) * K + swz;
  // prologue: first B tile into regs
  float4 rb[4][2];
#pragma unroll
  for (int i = 0; i < 4; i++) {
    rb[i][0] = *(const float4*)(w + woff[i]);
    rb[i][1] = *(const float4*)(w + woff[i] + 4);
  }
  for (int kt = 0; kt < K; kt += 64) {
#pragma unroll
    for (int i = 0; i < 8; i++)
      gload16(Ab + aoff[i] + kt, &As[((wv << 6) + (i << 3)) * 64]);
#pragma unroll
    for (int i = 0; i < 4; i++) {
      int idx = (srowB + i * 8) * 64 + (lane & 7) * 8;
      uint4 q;
      q.x = cvtpk(rb[i][0].x, rb[i][0].y);
      q.y = cvtpk(rb[i][0].z, rb[i][0].w);
      q.z = cvtpk(rb[i][1].x, rb[i][1].y);
      q.w = cvtpk(rb[i][1].z, rb[i][1].w);
      *(uint4*)&Bs[idx] = q;
    }
    __syncthreads();
    if (kt + 64 < K) {
#pragma unroll
      for (int i = 0; i < 4; i++) {
        rb[i][0] = *(const float4*)(w + woff[i] + kt + 64);
        rb[i][1] = *(const float4*)(w + woff[i] + kt + 68);
      }
    }
#pragma unroll
    for (int ks = 0; ks < 2; ks++) {
      bf16x8 af[4], bs[8];
#pragma unroll
      for (int m = 0; m < 4; m++) {
        int r = (wv << 6) + m * 16 + (lane & 15);
        af[m] = *(const bf16x8*)&As[r * 64 + (((ks * 4 + (lane >> 4)) ^ (r & 7)) * 8)];
      }
#pragma unroll
      for (int n = 0; n < 8; n++) {
        int r = n * 16 + (lane & 15);
        bs[n] = *(const bf16x8*)&Bs[r * 64 + (((ks * 4 + (lane >> 4)) ^ (r & 7)) * 8)];
      }
#pragma unroll
      for (int m = 0; m < 4; m++)
#pragma unroll
        for (int n = 0; n < 8; n++)
          acc[m][n] = __builtin_amdgcn_mfma_f32_16x16x32_bf16(af[m], bs[n], acc[m][n], 0, 0, 0);
    }
    __syncthreads();
  }
  // low-rank K-extension: acc += P@U^T (bf16, DMA both)
  for (int kt = 0; kt < RPAD; kt += 64) {
#pragma unroll
    for (int i = 0; i < 8; i++) {
      int gr = m0 + srowA + i * 8;
      if (gr >= cnt) gr = cnt - 1;
      gload16(Pq + (size_t)(roff + gr) * RPAD + swz + kt, &As[((wv << 6) + (i << 3)) * 64]);
    }
#pragma unroll
    for (int i = 0; i < 4; i++)
      gload16(uq + (size_t)(n0 + srowB + i * 8) * RPAD + swz + kt,
              &Bs[((wv << 5) + (i << 3)) * 64]);
    __syncthreads();
#pragma unroll
    for (int ks = 0; ks < 2; ks++) {
      bf16x8 af[4], bs[8];
#pragma unroll
      for (int m = 0; m < 4; m++) {
        int r = (wv << 6) + m * 16 + (lane & 15);
        af[m] = *(const bf16x8*)&As[r * 64 + (((ks * 4 + (lane >> 4)) ^ (r & 7)) * 8)];
      }
#pragma unroll
      for (int n = 0; n < 8; n++) {
        int r = n * 16 + (lane & 15);
        bs[n] = *(const bf16x8*)&Bs[r * 64 + (((ks * 4 + (lane >> 4)) ^ (r & 7)) * 8)];
      }
#pragma unroll
      for (int m = 0; m < 4; m++)
#pragma unroll
        for (int n = 0; n < 8; n++)
          acc[m][n] = __builtin_amdgcn_mfma_f32_16x16x32_bf16(af[m], bs[n], acc[m][n], 0, 0, 0);
    }
    __syncthreads();
  }
  // epilogue per MODE
#pragma unroll
  for (int m = 0; m < 4; m++) {
#pragma unroll
    for (int r4 = 0; r4 < 4; r4++) {
      int row = m0 + (wv << 6) + m * 16 + (lane >> 4) * 4 + r4;
      if (row < cnt) {
        size_t rbase = (size_t)(roff + row) * N + n0;
        if constexpr (MODE == 0) {
#pragma unroll
          for (int n = 0; n < 8; n++)
            outb[rbase + n * 16 + (lane & 15)] = f2bf(acc[m][n][r4]);
        } else if constexpr (MODE == 1) {
#pragma unroll
          for (int n = 0; n < 8; n++) {
            float g = bf2f(Gb[rbase + n * 16 + (lane & 15)]);
            float uu = acc[m][n][r4];
            float h = (g / (1.f + __expf(-g))) * uu;
            outb[rbase + n * 16 + (lane & 15)] = f2bf(h);
          }
        } else {
          float wgt = rowwgt[roff + row];
#pragma unroll
          for (int n = 0; n < 8; n++)
            outf[rbase + n * 16 + (lane & 15)] = acc[m][n][r4] * wgt;
        }
      }
    }
  }
}

// ---------------- combine: out[t] = y[row0] + y[row1] ----------------
__global__ void k_combine(const float* __restrict__ ybuf, const int* __restrict__ rowid,
                          float* __restrict__ out) {
  int idx = blockIdx.x * 256 + threadIdx.x;
  int t = idx >> 8;
  int c = (idx & 255) * 8;
  int r0 = rowid[t * 2], r1 = rowid[t * 2 + 1];
  const float* y0 = ybuf + (size_t)r0 * HH + c;
  const float* y1 = ybuf + (size_t)r1 * HH + c;
  float4 a0 = *(const float4*)y0, a1 = *(const float4*)(y0 + 4);
  float4 b0 = *(const float4*)y1, b1 = *(const float4*)(y1 + 4);
  float4 o0 = {a0.x + b0.x, a0.y + b0.y, a0.z + b0.z, a0.w + b0.w};
  float4 o1 = {a1.x + b1.x, a1.y + b1.y, a1.z + b1.z, a1.w + b1.w};
  float* o = out + (size_t)t * HH + c;
  *(float4*)o = o0;
  *(float4*)(o + 4) = o1;
}

extern "C" void kernel_launch(void* const* d_in, const int* in_sizes, int n_in,
                              void* d_out, int out_size, void* d_ws, size_t ws_size,
                              hipStream_t stream) {
  const float* x  = (const float*)d_in[0];
  const float* gw = (const float*)d_in[1];
  const float* W1 = (const float*)d_in[2];
  const float* W2 = (const float*)d_in[3];
  const float* W3 = (const float*)d_in[4];
  const float* U1 = (const float*)d_in[5];
  const float* V1 = (const float*)d_in[6];
  const float* U2 = (const float*)d_in[7];
  const float* V2 = (const float*)d_in[8];
  const float* U3 = (const float*)d_in[9];
  const float* V3 = (const float*)d_in[10];
  float* out = (float*)d_out;
  float* logits = out + (size_t)TT * HH;

  char* ws = (char*)d_ws;
  size_t off = 0;
  auto take = [&](size_t b) -> char* {
    char* p = ws + off;
    off += (b + 255) & ~(size_t)255;
    return p;
  };
  unsigned short* Xb   = (unsigned short*)take((size_t)TT * HH * 2);
  unsigned short* hmid = (unsigned short*)take((size_t)ROWS * II * 2);
  unsigned short* Gbuf = (unsigned short*)take((size_t)ROWS * II * 2);
  unsigned short* P1   = (unsigned short*)take((size_t)ROWS * RPAD * 2);
  unsigned short* P3   = (unsigned short*)take((size_t)ROWS * RPAD * 2);
  unsigned short* P2   = (unsigned short*)take((size_t)ROWS * RPAD * 2);
  float* ybuf          = (float*)take((size_t)ROWS * HH * 4);
  int* sel             = (int*)take((size_t)TT * 2 * 4);
  float* wtok          = (float*)take((size_t)TT * 2 * 4);
  int* rowsA           = (int*)take((size_t)ROWS * 4);
  float* rowwgt        = (float*)take((size_t)ROWS * 4);
  int* rowid           = (int*)take((size_t)TT * 2 * 4);
  int* meta            = (int*)take(1024);
  int* counts  = meta;
  int* offs    = meta + 16;
  int* curs    = meta + 32;
  unsigned short* V1b = (unsigned short*)take((size_t)EE * RR * HH * 2);
  unsigned short* V3b = (unsigned short*)take((size_t)EE * RR * HH * 2);
  unsigned short* V2b = (unsigned short*)take((size_t)EE * RR * II * 2);
  unsigned short* U1p = (unsigned short*)take((size_t)EE * II * RPAD * 2);
  unsigned short* U3p = (unsigned short*)take((size_t)EE * II * RPAD * 2);
  unsigned short* U2p = (unsigned short*)take((size_t)EE * HH * RPAD * 2);
  float* Pp           = (float*)take((size_t)8 * ROWS * RPAD * 4);

  hipMemsetAsync(counts, 0, EE * sizeof(int), stream);
  k_f2bf_flat<<<1024, 256, 0, stream>>>(V1, V1b, (long long)EE * RR * HH / 8);
  k_f2bf_flat<<<1024, 256, 0, stream>>>(V3, V3b, (long long)EE * RR * HH / 8);
  k_f2bf_flat<<<1024, 256, 0, stream>>>(V2, V2b, (long long)EE * RR * II / 8);
  k_upad<<<(EE * II * 24 + 255) / 256, 256, 0, stream>>>(U1, U1p, EE * II);
  k_upad<<<(EE * II * 24 + 255) / 256, 256, 0, stream>>>(U3, U3p, EE * II);
  k_upad<<<(EE * HH * 24 + 255) / 256, 256, 0, stream>>>(U2, U2p, EE * HH);
  k_router<<<TT, 256, 0, stream>>>(x, gw, logits, sel, wtok, counts);
  k_offsets<<<1, 64, 0, stream>>>(counts, offs, curs);
  k_build<<<TT / 256, 256, 0, stream>>>(sel, wtok, curs, rowsA, rowwgt, rowid);
  k_x2bf<<<2048, 256, 0, stream>>>(x, Xb);
  // P1/P3 = Xb(gathered) @ {V1,V3}^T : K=2048, split x4
  k_lowrank_sk<true><<<dim3(TT / 64, EE, 2 * 4), 256, 0, stream>>>(
      Xb, HH, HH, 512, 4, V1b, V3b, Pp, counts, offs, rowsA);
  k_lr_reduce<<<(2 * ROWS * 24 + 255) / 256, 256, 0, stream>>>(Pp, P1, P3, 4, 2);
  // gate then up (fused silu-mul in up's epilogue); n innermost (L3 W reuse)
  k_gemm_big<0><<<dim3(II / 128, ROWS / 256, EE), 256, 0, stream>>>(
      Xb, HH, II, W1, P1, U1p, nullptr, nullptr, Gbuf, nullptr, counts, offs, rowsA);
  k_gemm_big<1><<<dim3(II / 128, ROWS / 256, EE), 256, 0, stream>>>(
      Xb, HH, II, W3, P3, U3p, Gbuf, nullptr, hmid, nullptr, counts, offs, rowsA);
  // P2 = hmid @ V2^T : K=7168, split x8
  k_lowrank_sk<false><<<dim3(TT / 64, EE, 8), 256, 0, stream>>>(
      hmid, II, II, 896, 8, V2b, V2b, Pp, counts, offs, rowsA);
  k_lr_reduce<<<(ROWS * 24 + 255) / 256, 256, 0, stream>>>(Pp, P2, P2, 8, 1);
  // down-projection now also BM=256 (64 MFMA/K-step/wave on the longest K)
  k_gemm_big<2><<<dim3(HH / 128, ROWS / 256, EE), 256, 0, stream>>>(
      hmid, II, HH, W2, P2, U2p, nullptr, rowwgt, nullptr, ybuf, counts, offs, rowsA);
  k_combine<<<(TT * HH / 8) / 256, 256, 0, stream>>>(ybuf, rowid, out);
}